// Round 1
// baseline (222.905 us; speedup 1.0000x reference)
//
#include <hip/hip_runtime.h>
#include <hip/hip_bf16.h>

// out[r][c] = filt[r] * x[r][c]; x is (8192, 4096) fp32 row-major.
// Pure HBM-bandwidth kernel: 128 MiB read + 128 MiB write.
// One thread per float4 (16 B/lane coalescing sweet spot).
// M/4 = 1024 float4 per row -> row = i >> 10.

#define ROWS 8192
#define COLS 4096
#define N4   (ROWS * (COLS / 4))   // 8,388,608 float4 elements

__global__ __launch_bounds__(256) void diag_scale_kernel(
    const float4* __restrict__ x,
    const float*  __restrict__ filt,
    float4*       __restrict__ out) {
    int i = blockIdx.x * blockDim.x + threadIdx.x;
    // grid covers N4 exactly (N4 % 256 == 0), no bounds check needed
    float f = filt[i >> 10];          // COLS/4 = 1024 float4 per row
    float4 v = x[i];
    v.x *= f; v.y *= f; v.z *= f; v.w *= f;
    out[i] = v;
}

extern "C" void kernel_launch(void* const* d_in, const int* in_sizes, int n_in,
                              void* d_out, int out_size, void* d_ws, size_t ws_size,
                              hipStream_t stream) {
    const float4* x    = (const float4*)d_in[0];
    const float*  filt = (const float*)d_in[1];
    float4*       out  = (float4*)d_out;

    const int block = 256;
    const int grid  = N4 / block;    // 32768 blocks
    diag_scale_kernel<<<grid, block, 0, stream>>>(x, filt, out);
}

// Round 3
// 220.313 us; speedup vs baseline: 1.0118x; 1.0118x over previous
//
#include <hip/hip_runtime.h>
#include <hip/hip_bf16.h>

// out[r][c] = filt[r] * x[r][c]; x is (8192, 4096) fp32 row-major.
// Pure HBM-bandwidth kernel: 128 MiB read + 128 MiB write (floor ~43 us @6.3 TB/s).
//
// Design:
//  - One block per row (8192 blocks x 256 threads). filt[blockIdx.x] is
//    block-uniform -> scalar load.
//  - Each thread handles 4 float4 strided by 256 -> 4 independent 16 B loads
//    in flight (4x memory-level parallelism vs 1 in round 1).
//  - Nontemporal stores: `out` is never re-read, keep it from evicting x
//    in L2/L3. Uses a native clang vector type — __builtin_nontemporal_store
//    rejects HIP's float4 class (round-2 compile failure).

#define ROWS 8192
#define COLS 4096
#define C4   (COLS / 4)   // 1024 float4 per row

typedef float f4 __attribute__((ext_vector_type(4)));

__global__ __launch_bounds__(256) void diag_scale_kernel(
    const f4* __restrict__ x,
    const float* __restrict__ filt,
    f4* __restrict__ out) {
    const int   row  = blockIdx.x;
    const float f    = filt[row];                       // block-uniform scalar load
    const long  base = (long)row * C4 + threadIdx.x;    // float4 index

    f4 v[4];
#pragma unroll
    for (int k = 0; k < 4; ++k)
        v[k] = __builtin_nontemporal_load(&x[base + k * 256]);  // 4 loads in flight

#pragma unroll
    for (int k = 0; k < 4; ++k) {
        v[k] *= f;
        __builtin_nontemporal_store(v[k], &out[base + k * 256]);
    }
}

extern "C" void kernel_launch(void* const* d_in, const int* in_sizes, int n_in,
                              void* d_out, int out_size, void* d_ws, size_t ws_size,
                              hipStream_t stream) {
    const f4*    x    = (const f4*)d_in[0];
    const float* filt = (const float*)d_in[1];
    f4*          out  = (f4*)d_out;

    diag_scale_kernel<<<ROWS, 256, 0, stream>>>(x, filt, out);  // 1 block per row
}